// Round 6
// baseline (91.215 us; speedup 1.0000x reference)
//
#include <hip/hip_runtime.h>
#include <math.h>

#define PI_F 3.14159265358979323846f

constexpr int KM      = 16;
constexpr int NAG     = 64;
constexpr int TSTEPS  = 512;
constexpr int BB      = 32;
constexpr int TCHUNKS = 16;
constexpr int TPB     = TSTEPS / TCHUNKS;  // 32 timesteps per block
constexpr int TILE_T  = 4;
constexpr int TILE_P  = TILE_T * NAG;      // 256 points per LDS tile
constexpr int NTILES  = TPB / TILE_T;      // 8

// ws layout (floats): [0] = sum(u^2) accumulator, [16 .. 16+32*256) = c raw sums
constexpr int WS_C_OFF = 16;

__global__ __launch_bounds__(256)
void erg_main(const float* __restrict__ x, const float* __restrict__ u,
              float* __restrict__ ws)
{
    __shared__ float4 cosA[TILE_P][4];   // 16 KB, chunk-XOR-swizzled rows
    __shared__ float4 cosB[TILE_P][4];   // 16 KB
    __shared__ float4 red4[256];         // 4 KB cross-wave reduction buffer
    __shared__ float  redu[4];

    const int tid = threadIdx.x;
    const int bx  = blockIdx.x;
    const int b   = bx >> 4;      // batch
    const int tc  = bx & 15;      // t-chunk
    const int t0  = tc * TPB;

    // ---------------- u^2 partial (vectorized float4) ----------------
    float us = 0.f;
    const float4* u4 = (const float4*)u;
    #pragma unroll
    for (int r = 0; r < 4; ++r) {
        int idx  = (r << 8) + tid;          // 0..1023
        int trow = idx >> 5;                // 0..31
        int f4   = idx & 31;
        float4 v = u4[((size_t)(t0 + trow) * BB + b) * 32 + f4];
        us = fmaf(v.x, v.x, us); us = fmaf(v.y, v.y, us);
        us = fmaf(v.z, v.z, us); us = fmaf(v.w, v.w, us);
    }
    #pragma unroll
    for (int off = 32; off >= 1; off >>= 1) us += __shfl_xor(us, off, 64);
    if ((tid & 63) == 0) redu[tid >> 6] = us;
    __syncthreads();
    if (tid == 0) atomicAdd(&ws[0], redu[0] + redu[1] + redu[2] + redu[3]);

    // ---------------- main contraction ----------------
    float acc[8][8];
    #pragma unroll
    for (int i = 0; i < 8; ++i)
        #pragma unroll
        for (int j = 0; j < 8; ++j) acc[i][j] = 0.f;

    const int g   = tid & 3;         // output group: (gi,gj) 2x2 of 8x8 tiles
    const int ps  = tid >> 2;        // point slot 0..63
    const int gi  = g >> 1;
    const int gj  = g & 1;
    const int spr = (ps >> 1) & 3;   // read swizzle (p = q*64+ps -> (p>>1)&3 == (ps>>1)&3)

    const float2* x2  = (const float2*)x;
    const int tt_l = tid >> 6;       // 0..3 within tile
    const int n_l  = tid & 63;
    const int spw  = (tid >> 1) & 3; // write swizzle for p = tid

    for (int tile = 0; tile < NTILES; ++tile) {
        __syncthreads();
        // phase A: one point per thread, Chebyshev chain for both dims
        {
            int t = t0 + tile * TILE_T + tt_l;
            float2 xv = x2[(size_t)t * (BB * NAG) + b * NAG + n_l];
            float va[KM], vb[KM];
            va[0] = 1.f;  vb[0] = 1.f;
            va[1] = cosf(xv.x * PI_F);
            vb[1] = cosf(xv.y * PI_F);
            float ta  = 2.f * va[1];
            float tb2 = 2.f * vb[1];
            #pragma unroll
            for (int k = 2; k < KM; ++k) {
                va[k] = fmaf(ta,  va[k-1], -va[k-2]);
                vb[k] = fmaf(tb2, vb[k-1], -vb[k-2]);
            }
            cosA[tid][0 ^ spw] = make_float4(va[0],  va[1],  va[2],  va[3]);
            cosA[tid][1 ^ spw] = make_float4(va[4],  va[5],  va[6],  va[7]);
            cosA[tid][2 ^ spw] = make_float4(va[8],  va[9],  va[10], va[11]);
            cosA[tid][3 ^ spw] = make_float4(va[12], va[13], va[14], va[15]);
            cosB[tid][0 ^ spw] = make_float4(vb[0],  vb[1],  vb[2],  vb[3]);
            cosB[tid][1 ^ spw] = make_float4(vb[4],  vb[5],  vb[6],  vb[7]);
            cosB[tid][2 ^ spw] = make_float4(vb[8],  vb[9],  vb[10], vb[11]);
            cosB[tid][3 ^ spw] = make_float4(vb[12], vb[13], vb[14], vb[15]);
        }
        __syncthreads();
        // phase B: 8x8 register tile, 4 b128 reads per 64 FMAs
        #pragma unroll
        for (int q = 0; q < 4; ++q) {
            int p = (q << 6) + ps;
            float4 A0 = cosA[p][(2*gi)     ^ spr];
            float4 A1 = cosA[p][(2*gi + 1) ^ spr];
            float4 B0 = cosB[p][(2*gj)     ^ spr];
            float4 B1 = cosB[p][(2*gj + 1) ^ spr];
            float av[8] = {A0.x,A0.y,A0.z,A0.w,A1.x,A1.y,A1.z,A1.w};
            float bv[8] = {B0.x,B0.y,B0.z,B0.w,B1.x,B1.y,B1.z,B1.w};
            #pragma unroll
            for (int ii = 0; ii < 8; ++ii)
                #pragma unroll
                for (int jj = 0; jj < 8; ++jj)
                    acc[ii][jj] = fmaf(av[ii], bv[jj], acc[ii][jj]);
        }
    }

    // ---------------- block reduction over 64 ps slots ----------------
    // intra-wave: ps bits live at lane bits 2..5
    #pragma unroll
    for (int ii = 0; ii < 8; ++ii)
        #pragma unroll
        for (int jj = 0; jj < 8; ++jj) {
            float v = acc[ii][jj];
            v += __shfl_xor(v, 4,  64);
            v += __shfl_xor(v, 8,  64);
            v += __shfl_xor(v, 16, 64);
            v += __shfl_xor(v, 32, 64);
            acc[ii][jj] = v;
        }
    __syncthreads();
    if ((tid & 63) < 4) {            // lanes 0..3: g = lane
        int w = tid >> 6;
        float4* dst = &red4[(w * 4 + g) * 16];
        #pragma unroll
        for (int k4 = 0; k4 < 16; ++k4) {
            int ii = k4 >> 1, j0 = (k4 & 1) * 4;
            dst[k4] = make_float4(acc[ii][j0], acc[ii][j0+1], acc[ii][j0+2], acc[ii][j0+3]);
        }
    }
    __syncthreads();
    {
        int gp  = tid >> 6;          // group 0..3
        int idx = tid & 63;          // element within 8x8
        const float* rf = (const float*)red4;
        float s = rf[(0*4 + gp)*64 + idx] + rf[(1*4 + gp)*64 + idx]
                + rf[(2*4 + gp)*64 + idx] + rf[(3*4 + gp)*64 + idx];
        int ii = idx >> 3, jj = idx & 7;
        int i  = ((gp >> 1) << 3) + ii;
        int j  = ((gp &  1) << 3) + jj;
        atomicAdd(&ws[WS_C_OFF + ((b << 4) + i) * 16 + j], s);
    }
}

__global__ __launch_bounds__(256)
void erg_final(const float* __restrict__ ws, float* __restrict__ out)
{
    __shared__ float redu[4];
    const int tid = threadIdx.x;
    const int i = tid >> 4, j = tid & 15;

    const float inv_norm = (j == 0) ? 1.f : 1.41421356237309505f; // 1/sqrt(L/2), L=1
    float cd;
    if (i == 0 && j == 0)          cd = 1.f;
    else if ((i & 1) && (j & 1))   cd = -4.f / ((float)(i * j) * 9.86960440108936f); // -4/(ij*pi^2)
    else                           cd = 0.f;
    const float coef  = cd * inv_norm;           // coeffs_density = cd / norm
    const float scale = inv_norm * (1.f / 32768.f); // 1/(norm * N * T)

    float s = 0.f;
    #pragma unroll 8
    for (int b = 0; b < 32; ++b) {
        float S = ws[WS_C_OFF + ((b << 4) + i) * 16 + j];
        float d = fmaf(S, scale, -coef);
        s = fmaf(d, d, s);
    }
    #pragma unroll
    for (int off = 32; off >= 1; off >>= 1) s += __shfl_xor(s, off, 64);
    if ((tid & 63) == 0) redu[tid >> 6] = s;
    __syncthreads();
    if (tid == 0) {
        float tot  = redu[0] + redu[1] + redu[2] + redu[3];
        float loss = tot * (1.f / 8192.f)                       // mean over B*K*K
                   + ws[0] * (1e-3f / 2097152.f);               // REG*sum(u^2)/(2*N*T*B)
        out[0] = loss;
    }
}

extern "C" void kernel_launch(void* const* d_in, const int* in_sizes, int n_in,
                              void* d_out, int out_size, void* d_ws, size_t ws_size,
                              hipStream_t stream)
{
    (void)in_sizes; (void)n_in; (void)out_size; (void)ws_size;
    const float* x = (const float*)d_in[0];
    const float* u = (const float*)d_in[1];
    float* out = (float*)d_out;
    float* ws  = (float*)d_ws;

    hipMemsetAsync(d_ws, 0, (WS_C_OFF + BB * KM * KM) * sizeof(float), stream);
    erg_main<<<dim3(BB * TCHUNKS), dim3(256), 0, stream>>>(x, u, ws);
    erg_final<<<dim3(1), dim3(256), 0, stream>>>(ws, out);
}